// Round 12
// baseline (199.349 us; speedup 1.0000x reference)
//
#include <hip/hip_runtime.h>
#include <hip/hip_bf16.h>
#include <stdint.h>

#define T_DIM 12
#define N_DIM 2048
#define B_DIM 16
#define C_IN  64
#define C_OUT 64
#define EMB   16
#define P_DIM 1024   // B_DIM*C_IN

typedef __attribute__((ext_vector_type(8))) short short8;
typedef __attribute__((ext_vector_type(4))) float f32x4;

static __device__ __forceinline__ unsigned short f2bf(float f) {
  union { float f; uint32_t u; } v; v.f = f;
  uint32_t u = v.u;
  return (unsigned short)((u + 0x7fffu + ((u >> 16) & 1u)) >> 16);
}

static __device__ __forceinline__ float sigf(float x) {
  return __builtin_amdgcn_rcpf(1.0f + __expf(-x));
}

// async global->LDS, 16B per lane; lds ptr wave-uniform base (+lane*16 by HW)
static __device__ __forceinline__ void gload16(const void* g, void* l) {
  __builtin_amdgcn_global_load_lds(
      (const __attribute__((address_space(1))) unsigned int*)g,
      (__attribute__((address_space(3))) unsigned int*)l, 16, 0, 0);
}

template<bool MAX>
static __device__ __forceinline__ float block_red(float v, float* red) {
  #pragma unroll
  for (int o = 32; o > 0; o >>= 1) {
    float t = __shfl_down(v, o, 64);
    v = MAX ? fmaxf(v, t) : (v + t);
  }
  __syncthreads();
  if ((threadIdx.x & 63) == 0) red[threadIdx.x >> 6] = v;
  __syncthreads();
  float r = red[0];
  #pragma unroll
  for (int w = 1; w < 4; ++w) r = MAX ? fmaxf(r, red[w]) : (r + red[w]);
  return r;
}

// ---------------- stats: static row-sum d^-1/2, adaptive softmax row max/sumexp
__launch_bounds__(256)
__global__ void k_stats(const float* __restrict__ As, const float* __restrict__ E1,
                        const float* __restrict__ E2, float* __restrict__ dinv,
                        float* __restrict__ mx, float* __restrict__ se) {
  int n = blockIdx.x, tid = threadIdx.x;
  __shared__ float e1s[EMB];
  __shared__ float red[4];
  if (tid < EMB) e1s[tid] = E1[n * EMB + tid];
  __syncthreads();

  float rs = 0.f;
  #pragma unroll
  for (int i = 0; i < N_DIM / 256; ++i)
    rs += fmaxf(As[(size_t)n * N_DIM + i * 256 + tid], 0.f);

  float p[8];
  #pragma unroll
  for (int i = 0; i < 8; ++i) {
    int m = i * 256 + tid;
    float d = 0.f;
    #pragma unroll
    for (int e = 0; e < EMB; ++e) d += e1s[e] * E2[e * N_DIM + m];
    p[i] = fmaxf(d, 0.f);
  }
  float lmx = p[0];
  #pragma unroll
  for (int i = 1; i < 8; ++i) lmx = fmaxf(lmx, p[i]);
  float gmx = block_red<true>(lmx, red);
  float ls = 0.f;
  #pragma unroll
  for (int i = 0; i < 8; ++i) ls += expf(p[i] - gmx);
  float gse = block_red<false>(ls, red);
  float grs = block_red<false>(rs, red);
  if (tid == 0) {
    dinv[n] = rsqrtf(fmaxf(grs + 1.0f, 1e-12f));
    mx[n] = gmx;
    se[n] = gse;
  }
}

// ---------------- W^T (128 x 64) bf16
__launch_bounds__(256)
__global__ void k_wt(const float* __restrict__ W, unsigned short* __restrict__ WT) {
  int q = blockIdx.x * 256 + threadIdx.x;   // 8192
  int j = q >> 6, c = q & 63;
  WT[q] = f2bf(W[c * 128 + j]);
}

// ---------------- assemble A (2048x2048) in bf16
__launch_bounds__(256)
__global__ void k_abuild(const float* __restrict__ As, const float* __restrict__ E1,
                         const float* __restrict__ E2, const float* __restrict__ alpha,
                         const float* __restrict__ dinv, const float* __restrict__ mx,
                         const float* __restrict__ se, unsigned short* __restrict__ A) {
  int n = blockIdx.x, tid = threadIdx.x;
  __shared__ float e1s[EMB];
  if (tid < EMB) e1s[tid] = E1[n * EMB + tid];
  __syncthreads();
  float a = sigf(alpha[0]);
  float di_n = dinv[n], m_n = mx[n], inv_se = 1.f / se[n];
  float ca = a, cb = (1.f - a) * 0.5f;
  #pragma unroll
  for (int i = 0; i < 8; ++i) {
    int m = i * 256 + tid;
    float d = 0.f;
    #pragma unroll
    for (int e = 0; e < EMB; ++e) d += e1s[e] * E2[e * N_DIM + m];
    float soft = expf(fmaxf(d, 0.f) - m_n) * inv_se;
    float idm = (m == n) ? 1.f : 0.f;
    float sv = fmaxf(As[(size_t)n * N_DIM + m], 0.f) + idm;
    float val = ca * di_n * dinv[m] * sv + cb * (soft + idm);
    A[(size_t)n * N_DIM + m] = f2bf(val);
  }
}

// ---------------- x (t,m,p) f32 -> XT (t,p,m) bf16 via LDS tile transpose
__launch_bounds__(256)
__global__ void k_xt(const float* __restrict__ x, unsigned short* __restrict__ XT) {
  __shared__ float tile[64 * 65];
  int bid = blockIdx.x;
  int t = bid >> 9;
  int rem = bid & 511;
  int mt = rem >> 4, pt = rem & 15;
  int m0 = mt * 64, p0 = pt * 64;
  int tid = threadIdx.x;
  #pragma unroll
  for (int i = 0; i < 4; ++i) {
    int lin = i * 256 + tid;
    int mm = lin >> 4;
    int pp4 = lin & 15;
    const float4 v = *(const float4*)&x[(size_t)(t * N_DIM + m0 + mm) * P_DIM + p0 + pp4 * 4];
    tile[(pp4 * 4 + 0) * 65 + mm] = v.x;
    tile[(pp4 * 4 + 1) * 65 + mm] = v.y;
    tile[(pp4 * 4 + 2) * 65 + mm] = v.z;
    tile[(pp4 * 4 + 3) * 65 + mm] = v.w;
  }
  __syncthreads();
  #pragma unroll
  for (int i = 0; i < 2; ++i) {
    int lin = i * 256 + tid;
    int pp = lin >> 3;
    int mmb = (lin & 7) * 8;
    union { unsigned short s[8]; uint4 u; } pk;
    #pragma unroll
    for (int q = 0; q < 8; ++q) pk.s[q] = f2bf(tile[pp * 65 + mmb + q]);
    *(uint4*)&XT[(size_t)t * P_DIM * N_DIM + (size_t)(p0 + pp) * N_DIM + m0 + mmb] = pk.u;
  }
}

// ---------------- fused GEMM (R9 dbuf skeleton, 128x64/wave geometry):
// Y = A @ XT^T, then swiglu(Y@Wfc+b).
// BM=256, BN=128, BK=32, 256 thr = 4 waves (2Mx2N), wave 128x64, acc[8][4].
// LDS-BW model: 48KB ds_read + 24KB stage per 128 block-MFMA = 562 B/MFMA
// -> MfmaUtil ceiling ~55% (R7/R9's 64x64 geometry = 750 B/MFMA -> 41%,
// measured 40.5 three times). Dbuf 2x24KB; 64KB declared for Ys epilogue.
__launch_bounds__(256, 2)
__global__ void k_gemm(const unsigned short* __restrict__ A,   // 2048x2048 bf16
                       const unsigned short* __restrict__ XT,  // 12288 x 2048 bf16 (flat)
                       const unsigned short* __restrict__ WT,  // 128 x 64 bf16
                       const float* __restrict__ bfc,          // 128 f32
                       float* __restrict__ out) {
  __shared__ __align__(16) char lds[65536];   // dbuf 2x(A 16K + B 8K); Ys 64K overlay

  int v = blockIdx.x;
  int mb = v & 7;                 // fast axis: 8 consecutive blocks share B panel
  int pf = v >> 3;                // 0..95 (flat col group; never crosses t)
  int n0 = mb * 256;
  int p0f = pf * 128;
  int t = p0f >> 10;
  int b0 = (p0f & 1023) >> 6;

  int tid = threadIdx.x;
  int lane = tid & 63, wid = tid >> 6;
  int l15 = lane & 15, lc = lane >> 4;
  int wr = wid >> 1, wc = wid & 1;       // 2M x 2N
  int wsd = wid * 1024;

  // staging source (pre-swizzled global -> linear LDS dest = swizzled layout)
  // 64-B rows, 4 chunks of 16B; chunk' = chunk ^ ((row>>1)&3)  (2-way on read = free)
  int srow = tid >> 2;                           // 0..63
  int scol = ((tid & 3) ^ ((srow >> 1) & 3)) * 8;
  const unsigned short* gA = A + (size_t)(n0 + srow) * N_DIM + scol;
  const unsigned short* gB = XT + (size_t)(p0f + srow) * N_DIM + scol;

  // fragment read offsets (swizzled 64B rows); frag i at +i*1024
  int xr = ((l15 >> 1) & 3);
  int faoff = (wr * 128 + l15) * 64 + ((lc ^ xr) << 4);
  int fboff = (wc * 64 + l15) * 64 + ((lc ^ xr) << 4);

  f32x4 acc[8][4];
  #pragma unroll
  for (int m = 0; m < 8; ++m)
    #pragma unroll
    for (int n = 0; n < 4; ++n) acc[m][n] = (f32x4){0.f, 0.f, 0.f, 0.f};

  // prologue: stage tile 0 into buf0 (A: 4 stmts x 4KB, B: 2 stmts x 4KB)
  #pragma unroll
  for (int s = 0; s < 4; ++s) gload16(gA + s * 131072, lds + s * 4096 + wsd);
  #pragma unroll
  for (int s = 0; s < 2; ++s) gload16(gB + s * 131072, lds + 16384 + s * 4096 + wsd);
  __syncthreads();

  for (int j = 0; j < 64; ++j) {
    const char* bufc = lds + (j & 1) * 24576;
    char* bufn = lds + ((j + 1) & 1) * 24576;

    // issue next tile's staging early (drain at end-of-iter barrier is late)
    if (j < 63) {
      size_t ko = (size_t)(j + 1) * 32;
      #pragma unroll
      for (int s = 0; s < 4; ++s) gload16(gA + s * 131072 + ko, bufn + s * 4096 + wsd);
      #pragma unroll
      for (int s = 0; s < 2; ++s) gload16(gB + s * 131072 + ko, bufn + 16384 + s * 4096 + wsd);
    }

    // compute tile j from bufc
    short8 fb[4];
    #pragma unroll
    for (int ni = 0; ni < 4; ++ni)
      fb[ni] = *(const short8*)(bufc + 16384 + fboff + ni * 1024);
    #pragma unroll
    for (int mi = 0; mi < 8; ++mi) {
      short8 fa = *(const short8*)(bufc + faoff + mi * 1024);
      #pragma unroll
      for (int ni = 0; ni < 4; ++ni)
        acc[mi][ni] = __builtin_amdgcn_mfma_f32_16x16x32_bf16(fa, fb[ni], acc[mi][ni], 0, 0, 0);
    }

    __syncthreads();   // drains vmcnt (next tile staged) + orders buffer swap
  }

  // ---- epilogue: Ys (512 rows = n_local*2 + b_local, 64 cin, swizzled 128B rows)
  #pragma unroll
  for (int m = 0; m < 8; ++m) {
    #pragma unroll
    for (int n = 0; n < 4; ++n) {
      #pragma unroll
      for (int reg = 0; reg < 4; ++reg) {
        int nl = wr * 128 + m * 16 + (lc << 2) + reg;            // 0..255
        int cin = n * 16 + l15;                                  // 0..63
        int nb = nl * 2 + wc;                                    // 0..511
        int byte = nb * 128 + ((cin * 2) ^ ((nb & 7) << 4));
        *(unsigned short*)(lds + byte) = f2bf(acc[m][n][reg]);
      }
    }
  }
  __syncthreads();

  // GEMM2: (512 x 64) @ (64 x 128) + b, swiglu. W^T from global (L2-hot).
  short8 wf0[8], wf1[8];
  float bl[8];
  #pragma unroll
  for (int f2 = 0; f2 < 8; ++f2) {
    int jc = f2 * 16 + l15;
    wf0[f2] = *(const short8*)((const char*)WT + jc * 128 + lc * 16);
    wf1[f2] = *(const short8*)((const char*)WT + jc * 128 + 64 + lc * 16);
    bl[f2] = bfc[jc];
  }

  #pragma unroll
  for (int r2 = 0; r2 < 8; ++r2) {
    int row = wid * 128 + r2 * 16 + l15;
    int cb = (lc * 16) ^ ((row & 7) << 4);
    short8 a0 = *(const short8*)(lds + (row * 128 + cb));
    short8 a1 = *(const short8*)(lds + ((row * 128 + cb) ^ 64));
    f32x4 acc2[8];
    #pragma unroll
    for (int f2 = 0; f2 < 8; ++f2) {
      acc2[f2] = (f32x4){0.f, 0.f, 0.f, 0.f};
      acc2[f2] = __builtin_amdgcn_mfma_f32_16x16x32_bf16(a0, wf0[f2], acc2[f2], 0, 0, 0);
      acc2[f2] = __builtin_amdgcn_mfma_f32_16x16x32_bf16(a1, wf1[f2], acc2[f2], 0, 0, 0);
    }
    #pragma unroll
    for (int f2 = 0; f2 < 4; ++f2) {
      #pragma unroll
      for (int reg = 0; reg < 4; ++reg) {
        int nb = wid * 128 + r2 * 16 + (lc << 2) + reg;
        float zl = acc2[f2][reg] + bl[f2];
        float zr = acc2[f2 + 4][reg] + bl[f2 + 4];
        float ov = zl * sigf(zr);
        int n = n0 + (nb >> 1);
        int b = b0 + (nb & 1);
        int co = f2 * 16 + l15;
        out[(size_t)((t * N_DIM + n) * B_DIM + b) * C_OUT + co] = ov;
      }
    }
  }
}

extern "C" void kernel_launch(void* const* d_in, const int* in_sizes, int n_in,
                              void* d_out, int out_size, void* d_ws, size_t ws_size,
                              hipStream_t stream) {
  const float* x  = (const float*)d_in[0];
  const float* As = (const float*)d_in[1];
  const float* E1 = (const float*)d_in[2];
  const float* E2 = (const float*)d_in[3];
  const float* al = (const float*)d_in[4];
  const float* W  = (const float*)d_in[5];
  const float* bf = (const float*)d_in[6];
  float* out = (float*)d_out;

  char* ws = (char*)d_ws;
  unsigned short* XT = (unsigned short*)ws;                       // 50,331,648 B
  unsigned short* Ab = (unsigned short*)(ws + 50331648);          //  8,388,608 B
  unsigned short* WT = (unsigned short*)(ws + 58720256);          //     16,384 B
  float* dinv = (float*)(ws + 58736640);
  float* mx   = (float*)(ws + 58744832);
  float* se   = (float*)(ws + 58753024);

  k_stats<<<dim3(2048), dim3(256), 0, stream>>>(As, E1, E2, dinv, mx, se);
  k_wt<<<dim3(32), dim3(256), 0, stream>>>(W, WT);
  k_abuild<<<dim3(2048), dim3(256), 0, stream>>>(As, E1, E2, al, dinv, mx, se, Ab);
  k_xt<<<dim3(6144), dim3(256), 0, stream>>>(x, XT);
  k_gemm<<<dim3(768), dim3(256), 0, stream>>>(Ab, XT, WT, bf, out);
}

// Round 13
// 165.404 us; speedup vs baseline: 1.2052x; 1.2052x over previous
//
#include <hip/hip_runtime.h>
#include <hip/hip_bf16.h>
#include <stdint.h>

#define T_DIM 12
#define N_DIM 2048
#define B_DIM 16
#define C_IN  64
#define C_OUT 64
#define EMB   16
#define P_DIM 1024   // B_DIM*C_IN

typedef __attribute__((ext_vector_type(8))) short short8;
typedef __attribute__((ext_vector_type(4))) float f32x4;

static __device__ __forceinline__ unsigned short f2bf(float f) {
  union { float f; uint32_t u; } v; v.f = f;
  uint32_t u = v.u;
  return (unsigned short)((u + 0x7fffu + ((u >> 16) & 1u)) >> 16);
}

static __device__ __forceinline__ float sigf(float x) {
  return __builtin_amdgcn_rcpf(1.0f + __expf(-x));
}

// async global->LDS, 16B per lane; lds ptr wave-uniform base (+lane*16 by HW)
static __device__ __forceinline__ void gload16(const void* g, void* l) {
  __builtin_amdgcn_global_load_lds(
      (const __attribute__((address_space(1))) unsigned int*)g,
      (__attribute__((address_space(3))) unsigned int*)l, 16, 0, 0);
}

template<bool MAX>
static __device__ __forceinline__ float block_red(float v, float* red) {
  #pragma unroll
  for (int o = 32; o > 0; o >>= 1) {
    float t = __shfl_down(v, o, 64);
    v = MAX ? fmaxf(v, t) : (v + t);
  }
  __syncthreads();
  if ((threadIdx.x & 63) == 0) red[threadIdx.x >> 6] = v;
  __syncthreads();
  float r = red[0];
  #pragma unroll
  for (int w = 1; w < 4; ++w) r = MAX ? fmaxf(r, red[w]) : (r + red[w]);
  return r;
}

// ---------------- fused prep: [0,6144) x-transpose | [6144,8192) dinv | [8192,8224) W^T
__launch_bounds__(256)
__global__ void k_prep(const float* __restrict__ x, unsigned short* __restrict__ XT,
                       const float* __restrict__ As, float* __restrict__ dinv,
                       const float* __restrict__ W, unsigned short* __restrict__ WT) {
  __shared__ float smf[64 * 65];
  int bid = blockIdx.x;
  int tid = threadIdx.x;

  if (bid < 6144) {
    // ---- x (t,m,p) f32 -> XT (t,p,m) bf16 via LDS tile transpose
    int t = bid >> 9;
    int rem = bid & 511;
    int mt = rem >> 4, pt = rem & 15;
    int m0 = mt * 64, p0 = pt * 64;
    #pragma unroll
    for (int i = 0; i < 4; ++i) {
      int lin = i * 256 + tid;
      int mm = lin >> 4;
      int pp4 = lin & 15;
      const float4 v = *(const float4*)&x[(size_t)(t * N_DIM + m0 + mm) * P_DIM + p0 + pp4 * 4];
      smf[(pp4 * 4 + 0) * 65 + mm] = v.x;
      smf[(pp4 * 4 + 1) * 65 + mm] = v.y;
      smf[(pp4 * 4 + 2) * 65 + mm] = v.z;
      smf[(pp4 * 4 + 3) * 65 + mm] = v.w;
    }
    __syncthreads();
    #pragma unroll
    for (int i = 0; i < 2; ++i) {
      int lin = i * 256 + tid;
      int pp = lin >> 3;
      int mmb = (lin & 7) * 8;
      union { unsigned short s[8]; uint4 u; } pk;
      #pragma unroll
      for (int q = 0; q < 8; ++q) pk.s[q] = f2bf(smf[pp * 65 + mmb + q]);
      *(uint4*)&XT[(size_t)t * P_DIM * N_DIM + (size_t)(p0 + pp) * N_DIM + m0 + mmb] = pk.u;
    }
  } else if (bid < 8192) {
    // ---- dinv[n] from static row sums
    int n = bid - 6144;
    float rs = 0.f;
    #pragma unroll
    for (int i = 0; i < N_DIM / 256; ++i)
      rs += fmaxf(As[(size_t)n * N_DIM + i * 256 + tid], 0.f);
    float grs = block_red<false>(rs, smf);
    if (tid == 0) dinv[n] = rsqrtf(fmaxf(grs + 1.0f, 1e-12f));
  } else {
    // ---- W^T (128 x 64) bf16
    int q = (bid - 8192) * 256 + tid;   // 8192 elems
    int j = q >> 6, c = q & 63;
    WT[q] = f2bf(W[c * 128 + j]);
  }
}

// ---------------- assemble A (2048x2048) bf16, softmax stats computed inline
__launch_bounds__(256)
__global__ void k_abuild(const float* __restrict__ As, const float* __restrict__ E1,
                         const float* __restrict__ E2, const float* __restrict__ alpha,
                         const float* __restrict__ dinv, unsigned short* __restrict__ A) {
  int n = blockIdx.x, tid = threadIdx.x;
  __shared__ float e1s[EMB];
  __shared__ float red[4];
  if (tid < EMB) e1s[tid] = E1[n * EMB + tid];
  __syncthreads();

  // adaptive row: d[m] = relu(E1[n]·E2[:,m]) for this block's 8 m-chunks
  float p[8];
  #pragma unroll
  for (int i = 0; i < 8; ++i) {
    int m = i * 256 + tid;
    float d = 0.f;
    #pragma unroll
    for (int e = 0; e < EMB; ++e) d += e1s[e] * E2[e * N_DIM + m];
    p[i] = fmaxf(d, 0.f);
  }
  float lmx = p[0];
  #pragma unroll
  for (int i = 1; i < 8; ++i) lmx = fmaxf(lmx, p[i]);
  float gmx = block_red<true>(lmx, red);
  float ls = 0.f;
  #pragma unroll
  for (int i = 0; i < 8; ++i) ls += expf(p[i] - gmx);
  float gse = block_red<false>(ls, red);

  float a = sigf(alpha[0]);
  float di_n = dinv[n], inv_se = 1.f / gse;
  float ca = a, cb = (1.f - a) * 0.5f;
  #pragma unroll
  for (int i = 0; i < 8; ++i) {
    int m = i * 256 + tid;
    float soft = expf(p[i] - gmx) * inv_se;
    float idm = (m == n) ? 1.f : 0.f;
    float sv = fmaxf(As[(size_t)n * N_DIM + m], 0.f) + idm;
    float val = ca * di_n * dinv[m] * sv + cb * (soft + idm);
    A[(size_t)n * N_DIM + m] = f2bf(val);
  }
}

// ---------------- fused GEMM (R7, verbatim champion): Y = A @ XT_flat^T, swiglu(Y@Wfc+b)
// BM=BN=128, BK=64, 256 thr = 4 waves (2Mx2N), wave 64x64, acc[4][4].
// Single-buffer 2-barrier loop (high TLP: 3+ blocks/CU, grid 1536 = 2 exact
// rounds). T2 swizzle via pre-swizzled global src + swizzled ds_read.
// Measured (R7): 117 us, MfmaUtil 40.5% = its LDS-BW ceiling (750 B/MFMA).
__launch_bounds__(256, 3)
__global__ void k_gemm(const unsigned short* __restrict__ A,   // 2048x2048 bf16
                       const unsigned short* __restrict__ XT,  // 12288 x 2048 bf16 (flat)
                       const unsigned short* __restrict__ WT,  // 128 x 64 bf16
                       const float* __restrict__ bfc,          // 128 f32
                       float* __restrict__ out) {
  __shared__ __align__(16) char lds[32768];   // A 16K + B 16K; Ys 32K overlay

  int v = blockIdx.x;
  int mb = v & 15;
  int pf = v >> 4;                // 0..95 (flat col group; never crosses t)
  int n0 = mb * 128;
  int p0f = pf * 128;
  int t = p0f >> 10;
  int b0 = (p0f & 1023) >> 6;

  int tid = threadIdx.x;
  int lane = tid & 63, wid = tid >> 6;
  int wr = wid >> 1, wc = wid & 1;       // 2M x 2N
  int wsd = wid * 1024;

  // staging source (pre-swizzled global -> linear LDS dest = swizzled layout)
  int srow = tid >> 3;                           // 0..31
  int scol = ((tid & 7) ^ (srow & 7)) * 8;       // swizzled 16B chunk in K=64
  const unsigned short* gA = A + (size_t)(n0 + srow) * N_DIM + scol;
  const unsigned short* gB = XT + (size_t)(p0f + srow) * N_DIM + scol;

  // fragment read offsets (swizzled 128B rows)
  int rsw = ((lane >> 4) * 16) ^ ((lane & 7) << 4);
  int faoff = (wr * 64 + (lane & 15)) * 128 + rsw;
  int fboff = (wc * 64 + (lane & 15)) * 128 + rsw;

  f32x4 acc[4][4];
  #pragma unroll
  for (int m = 0; m < 4; ++m)
    #pragma unroll
    for (int n = 0; n < 4; ++n) acc[m][n] = (f32x4){0.f, 0.f, 0.f, 0.f};

  for (int j = 0; j < 32; ++j) {
    size_t ko = (size_t)j * 64;
    #pragma unroll
    for (int s = 0; s < 4; ++s) gload16(gA + s * 65536 + ko, lds + s * 4096 + wsd);
    #pragma unroll
    for (int s = 0; s < 4; ++s) gload16(gB + s * 65536 + ko, lds + 16384 + s * 4096 + wsd);
    __syncthreads();   // drains vmcnt -> staged tile visible

    short8 fa[4][2], fb[4][2];
    #pragma unroll
    for (int mi = 0; mi < 4; ++mi)
      #pragma unroll
      for (int kk = 0; kk < 2; ++kk)
        fa[mi][kk] = *(const short8*)(lds + ((faoff + mi * 2048) ^ (kk * 64)));
    #pragma unroll
    for (int ni = 0; ni < 4; ++ni)
      #pragma unroll
      for (int kk = 0; kk < 2; ++kk)
        fb[ni][kk] = *(const short8*)(lds + 16384 + ((fboff + ni * 2048) ^ (kk * 64)));
    #pragma unroll
    for (int mi = 0; mi < 4; ++mi)
      #pragma unroll
      for (int ni = 0; ni < 4; ++ni) {
        acc[mi][ni] = __builtin_amdgcn_mfma_f32_16x16x32_bf16(fa[mi][0], fb[ni][0], acc[mi][ni], 0, 0, 0);
        acc[mi][ni] = __builtin_amdgcn_mfma_f32_16x16x32_bf16(fa[mi][1], fb[ni][1], acc[mi][ni], 0, 0, 0);
      }
    __syncthreads();   // all reads done before next stage overwrites
  }

  // ---- epilogue: Ys (256 rows = n_local*2 + b_local, 64 cin, swizzled 128B rows)
  #pragma unroll
  for (int m = 0; m < 4; ++m) {
    #pragma unroll
    for (int n = 0; n < 4; ++n) {
      #pragma unroll
      for (int reg = 0; reg < 4; ++reg) {
        int rl = wr * 64 + m * 16 + ((lane >> 4) << 2) + reg;    // 0..127
        int cin = n * 16 + (lane & 15);                          // 0..63
        int nb = rl * 2 + wc;                                    // 0..255
        int byte = nb * 128 + ((cin * 2) ^ ((nb & 7) << 4));
        *(unsigned short*)(lds + byte) = f2bf(acc[m][n][reg]);
      }
    }
  }
  __syncthreads();

  // GEMM2: (256 x 64) @ (64 x 128) + b, swiglu. W^T from global (L2-hot).
  short8 wf0[8], wf1[8];
  float bl[8];
  #pragma unroll
  for (int f2 = 0; f2 < 8; ++f2) {
    int jc = f2 * 16 + (lane & 15);
    wf0[f2] = *(const short8*)((const char*)WT + jc * 128 + (lane >> 4) * 16);
    wf1[f2] = *(const short8*)((const char*)WT + jc * 128 + 64 + (lane >> 4) * 16);
    bl[f2] = bfc[jc];
  }

  #pragma unroll
  for (int r2 = 0; r2 < 4; ++r2) {
    int row = wid * 64 + r2 * 16 + (lane & 15);
    int cb = ((lane >> 4) * 16) ^ ((row & 7) << 4);
    short8 a0 = *(const short8*)(lds + (row * 128 + cb));
    short8 a1 = *(const short8*)(lds + ((row * 128 + cb) ^ 64));
    f32x4 acc2[8];
    #pragma unroll
    for (int f2 = 0; f2 < 8; ++f2) {
      acc2[f2] = (f32x4){0.f, 0.f, 0.f, 0.f};
      acc2[f2] = __builtin_amdgcn_mfma_f32_16x16x32_bf16(a0, wf0[f2], acc2[f2], 0, 0, 0);
      acc2[f2] = __builtin_amdgcn_mfma_f32_16x16x32_bf16(a1, wf1[f2], acc2[f2], 0, 0, 0);
    }
    #pragma unroll
    for (int f2 = 0; f2 < 4; ++f2) {
      #pragma unroll
      for (int reg = 0; reg < 4; ++reg) {
        int nb = wid * 64 + r2 * 16 + ((lane >> 4) << 2) + reg;
        float zl = acc2[f2][reg] + bl[f2];
        float zr = acc2[f2 + 4][reg] + bl[f2 + 4];
        float ov = zl * sigf(zr);
        int n = n0 + (nb >> 1);
        int b = b0 + (nb & 1);
        int co = f2 * 16 + (lane & 15);
        out[(size_t)((t * N_DIM + n) * B_DIM + b) * C_OUT + co] = ov;
      }
    }
  }
}

extern "C" void kernel_launch(void* const* d_in, const int* in_sizes, int n_in,
                              void* d_out, int out_size, void* d_ws, size_t ws_size,
                              hipStream_t stream) {
  const float* x  = (const float*)d_in[0];
  const float* As = (const float*)d_in[1];
  const float* E1 = (const float*)d_in[2];
  const float* E2 = (const float*)d_in[3];
  const float* al = (const float*)d_in[4];
  const float* W  = (const float*)d_in[5];
  const float* bf = (const float*)d_in[6];
  float* out = (float*)d_out;

  char* ws = (char*)d_ws;
  unsigned short* XT = (unsigned short*)ws;                       // 50,331,648 B
  unsigned short* Ab = (unsigned short*)(ws + 50331648);          //  8,388,608 B
  unsigned short* WT = (unsigned short*)(ws + 58720256);          //     16,384 B
  float* dinv = (float*)(ws + 58736640);

  k_prep<<<dim3(8224), dim3(256), 0, stream>>>(x, XT, As, dinv, W, WT);
  k_abuild<<<dim3(2048), dim3(256), 0, stream>>>(As, E1, E2, al, dinv, Ab);
  k_gemm<<<dim3(1536), dim3(256), 0, stream>>>(Ab, XT, WT, bf, out);
}

// Round 14
// 165.169 us; speedup vs baseline: 1.2069x; 1.0014x over previous
//
#include <hip/hip_runtime.h>
#include <hip/hip_bf16.h>
#include <stdint.h>

#define T_DIM 12
#define N_DIM 2048
#define B_DIM 16
#define C_IN  64
#define C_OUT 64
#define EMB   16
#define P_DIM 1024   // B_DIM*C_IN

typedef __attribute__((ext_vector_type(8))) short short8;
typedef __attribute__((ext_vector_type(4))) float f32x4;

static __device__ __forceinline__ unsigned short f2bf(float f) {
  union { float f; uint32_t u; } v; v.f = f;
  uint32_t u = v.u;
  return (unsigned short)((u + 0x7fffu + ((u >> 16) & 1u)) >> 16);
}

static __device__ __forceinline__ float sigf(float x) {
  return __builtin_amdgcn_rcpf(1.0f + __expf(-x));
}

// async global->LDS, 16B per lane; lds ptr wave-uniform base (+lane*16 by HW)
static __device__ __forceinline__ void gload16(const void* g, void* l) {
  __builtin_amdgcn_global_load_lds(
      (const __attribute__((address_space(1))) unsigned int*)g,
      (__attribute__((address_space(3))) unsigned int*)l, 16, 0, 0);
}

template<bool MAX>
static __device__ __forceinline__ float block_red(float v, float* red) {
  #pragma unroll
  for (int o = 32; o > 0; o >>= 1) {
    float t = __shfl_down(v, o, 64);
    v = MAX ? fmaxf(v, t) : (v + t);
  }
  __syncthreads();
  if ((threadIdx.x & 63) == 0) red[threadIdx.x >> 6] = v;
  __syncthreads();
  float r = red[0];
  #pragma unroll
  for (int w = 1; w < 4; ++w) r = MAX ? fmaxf(r, red[w]) : (r + red[w]);
  return r;
}

// ---------------- k_dinv: [0,2048) static row-sum d^-1/2 | [2048,2080) W^T pack
__launch_bounds__(256)
__global__ void k_dinv(const float* __restrict__ As, float* __restrict__ dinv,
                       const float* __restrict__ W, unsigned short* __restrict__ WT) {
  __shared__ float red[4];
  int bid = blockIdx.x, tid = threadIdx.x;
  if (bid < 2048) {
    int n = bid;
    float rs = 0.f;
    #pragma unroll
    for (int i = 0; i < N_DIM / 256; ++i)
      rs += fmaxf(As[(size_t)n * N_DIM + i * 256 + tid], 0.f);
    float grs = block_red<false>(rs, red);
    if (tid == 0) dinv[n] = rsqrtf(fmaxf(grs + 1.0f, 1e-12f));
  } else {
    int q = (bid - 2048) * 256 + tid;   // 8192 elems
    int j = q >> 6, c = q & 63;
    WT[q] = f2bf(W[c * 128 + j]);
  }
}

// ---------------- k_prep2: [0,2048) A-assemble (inline softmax) | [2048,8192) x-transpose
// abuild (VALU/L2-bound) overlaps xt (HBM-bound) inside one launch.
__launch_bounds__(256)
__global__ void k_prep2(const float* __restrict__ As, const float* __restrict__ E1,
                        const float* __restrict__ E2, const float* __restrict__ alpha,
                        const float* __restrict__ dinv, unsigned short* __restrict__ A,
                        const float* __restrict__ x, unsigned short* __restrict__ XT) {
  __shared__ float smf[64 * 65];
  int bid = blockIdx.x, tid = threadIdx.x;

  if (bid < 2048) {
    // ---- assemble A row n (2048 cols), softmax stats inline
    int n = bid;
    if (tid < EMB) smf[4 + tid] = E1[n * EMB + tid];
    __syncthreads();
    float e1s[EMB];
    #pragma unroll
    for (int e = 0; e < EMB; ++e) e1s[e] = smf[4 + e];

    float p[8];
    #pragma unroll
    for (int i = 0; i < 8; ++i) {
      int m = i * 256 + tid;
      float d = 0.f;
      #pragma unroll
      for (int e = 0; e < EMB; ++e) d += e1s[e] * E2[e * N_DIM + m];
      p[i] = fmaxf(d, 0.f);
    }
    float lmx = p[0];
    #pragma unroll
    for (int i = 1; i < 8; ++i) lmx = fmaxf(lmx, p[i]);
    float gmx = block_red<true>(lmx, smf);
    float ls = 0.f;
    #pragma unroll
    for (int i = 0; i < 8; ++i) ls += expf(p[i] - gmx);
    float gse = block_red<false>(ls, smf);

    float a = sigf(alpha[0]);
    float di_n = dinv[n], inv_se = 1.f / gse;
    float ca = a, cb = (1.f - a) * 0.5f;
    #pragma unroll
    for (int i = 0; i < 8; ++i) {
      int m = i * 256 + tid;
      float soft = expf(p[i] - gmx) * inv_se;
      float idm = (m == n) ? 1.f : 0.f;
      float sv = fmaxf(As[(size_t)n * N_DIM + m], 0.f) + idm;
      float val = ca * di_n * dinv[m] * sv + cb * (soft + idm);
      A[(size_t)n * N_DIM + m] = f2bf(val);
    }
  } else {
    // ---- x (t,m,p) f32 -> XT (t,p,m) bf16 via LDS tile transpose
    int xb = bid - 2048;
    int t = xb >> 9;
    int rem = xb & 511;
    int mt = rem >> 4, pt = rem & 15;
    int m0 = mt * 64, p0 = pt * 64;
    #pragma unroll
    for (int i = 0; i < 4; ++i) {
      int lin = i * 256 + tid;
      int mm = lin >> 4;
      int pp4 = lin & 15;
      const float4 v = *(const float4*)&x[(size_t)(t * N_DIM + m0 + mm) * P_DIM + p0 + pp4 * 4];
      smf[(pp4 * 4 + 0) * 65 + mm] = v.x;
      smf[(pp4 * 4 + 1) * 65 + mm] = v.y;
      smf[(pp4 * 4 + 2) * 65 + mm] = v.z;
      smf[(pp4 * 4 + 3) * 65 + mm] = v.w;
    }
    __syncthreads();
    #pragma unroll
    for (int i = 0; i < 2; ++i) {
      int lin = i * 256 + tid;
      int pp = lin >> 3;
      int mmb = (lin & 7) * 8;
      union { unsigned short s[8]; uint4 u; } pk;
      #pragma unroll
      for (int q = 0; q < 8; ++q) pk.s[q] = f2bf(smf[pp * 65 + mmb + q]);
      *(uint4*)&XT[(size_t)t * P_DIM * N_DIM + (size_t)(p0 + pp) * N_DIM + m0 + mmb] = pk.u;
    }
  }
}

// ---------------- fused GEMM (R7, verbatim champion): Y = A @ XT_flat^T, swiglu(Y@Wfc+b)
// BM=BN=128, BK=64, 256 thr = 4 waves (2Mx2N), wave 64x64, acc[4][4].
// Single-buffer 2-barrier loop (high TLP: 3+ blocks/CU, grid 1536 = 2 exact
// rounds). T2 swizzle via pre-swizzled global src + swizzled ds_read.
// Measured: 117 us, MfmaUtil 41% = its LDS-BW ceiling (96KB/iter / 155cy
// = 634 B/cy demand vs 256 B/cy supply). Frozen: geometry variants are
// VGPR-blocked (R12), B-direct is scatter-blocked (R6/R8).
__launch_bounds__(256, 3)
__global__ void k_gemm(const unsigned short* __restrict__ A,   // 2048x2048 bf16
                       const unsigned short* __restrict__ XT,  // 12288 x 2048 bf16 (flat)
                       const unsigned short* __restrict__ WT,  // 128 x 64 bf16
                       const float* __restrict__ bfc,          // 128 f32
                       float* __restrict__ out) {
  __shared__ __align__(16) char lds[32768];   // A 16K + B 16K; Ys 32K overlay

  int v = blockIdx.x;
  int mb = v & 15;
  int pf = v >> 4;                // 0..95 (flat col group; never crosses t)
  int n0 = mb * 128;
  int p0f = pf * 128;
  int t = p0f >> 10;
  int b0 = (p0f & 1023) >> 6;

  int tid = threadIdx.x;
  int lane = tid & 63, wid = tid >> 6;
  int wr = wid >> 1, wc = wid & 1;       // 2M x 2N
  int wsd = wid * 1024;

  // staging source (pre-swizzled global -> linear LDS dest = swizzled layout)
  int srow = tid >> 3;                           // 0..31
  int scol = ((tid & 7) ^ (srow & 7)) * 8;       // swizzled 16B chunk in K=64
  const unsigned short* gA = A + (size_t)(n0 + srow) * N_DIM + scol;
  const unsigned short* gB = XT + (size_t)(p0f + srow) * N_DIM + scol;

  // fragment read offsets (swizzled 128B rows)
  int rsw = ((lane >> 4) * 16) ^ ((lane & 7) << 4);
  int faoff = (wr * 64 + (lane & 15)) * 128 + rsw;
  int fboff = (wc * 64 + (lane & 15)) * 128 + rsw;

  f32x4 acc[4][4];
  #pragma unroll
  for (int m = 0; m < 4; ++m)
    #pragma unroll
    for (int n = 0; n < 4; ++n) acc[m][n] = (f32x4){0.f, 0.f, 0.f, 0.f};

  for (int j = 0; j < 32; ++j) {
    size_t ko = (size_t)j * 64;
    #pragma unroll
    for (int s = 0; s < 4; ++s) gload16(gA + s * 65536 + ko, lds + s * 4096 + wsd);
    #pragma unroll
    for (int s = 0; s < 4; ++s) gload16(gB + s * 65536 + ko, lds + 16384 + s * 4096 + wsd);
    __syncthreads();   // drains vmcnt -> staged tile visible

    short8 fa[4][2], fb[4][2];
    #pragma unroll
    for (int mi = 0; mi < 4; ++mi)
      #pragma unroll
      for (int kk = 0; kk < 2; ++kk)
        fa[mi][kk] = *(const short8*)(lds + ((faoff + mi * 2048) ^ (kk * 64)));
    #pragma unroll
    for (int ni = 0; ni < 4; ++ni)
      #pragma unroll
      for (int kk = 0; kk < 2; ++kk)
        fb[ni][kk] = *(const short8*)(lds + 16384 + ((fboff + ni * 2048) ^ (kk * 64)));
    #pragma unroll
    for (int mi = 0; mi < 4; ++mi)
      #pragma unroll
      for (int ni = 0; ni < 4; ++ni) {
        acc[mi][ni] = __builtin_amdgcn_mfma_f32_16x16x32_bf16(fa[mi][0], fb[ni][0], acc[mi][ni], 0, 0, 0);
        acc[mi][ni] = __builtin_amdgcn_mfma_f32_16x16x32_bf16(fa[mi][1], fb[ni][1], acc[mi][ni], 0, 0, 0);
      }
    __syncthreads();   // all reads done before next stage overwrites
  }

  // ---- epilogue: Ys (256 rows = n_local*2 + b_local, 64 cin, swizzled 128B rows)
  #pragma unroll
  for (int m = 0; m < 4; ++m) {
    #pragma unroll
    for (int n = 0; n < 4; ++n) {
      #pragma unroll
      for (int reg = 0; reg < 4; ++reg) {
        int rl = wr * 64 + m * 16 + ((lane >> 4) << 2) + reg;    // 0..127
        int cin = n * 16 + (lane & 15);                          // 0..63
        int nb = rl * 2 + wc;                                    // 0..255
        int byte = nb * 128 + ((cin * 2) ^ ((nb & 7) << 4));
        *(unsigned short*)(lds + byte) = f2bf(acc[m][n][reg]);
      }
    }
  }
  __syncthreads();

  // GEMM2: (256 x 64) @ (64 x 128) + b, swiglu. W^T from global (L2-hot).
  short8 wf0[8], wf1[8];
  float bl[8];
  #pragma unroll
  for (int f2 = 0; f2 < 8; ++f2) {
    int jc = f2 * 16 + (lane & 15);
    wf0[f2] = *(const short8*)((const char*)WT + jc * 128 + (lane >> 4) * 16);
    wf1[f2] = *(const short8*)((const char*)WT + jc * 128 + 64 + (lane >> 4) * 16);
    bl[f2] = bfc[jc];
  }

  #pragma unroll
  for (int r2 = 0; r2 < 4; ++r2) {
    int row = wid * 64 + r2 * 16 + (lane & 15);
    int cb = ((lane >> 4) * 16) ^ ((row & 7) << 4);
    short8 a0 = *(const short8*)(lds + (row * 128 + cb));
    short8 a1 = *(const short8*)(lds + ((row * 128 + cb) ^ 64));
    f32x4 acc2[8];
    #pragma unroll
    for (int f2 = 0; f2 < 8; ++f2) {
      acc2[f2] = (f32x4){0.f, 0.f, 0.f, 0.f};
      acc2[f2] = __builtin_amdgcn_mfma_f32_16x16x32_bf16(a0, wf0[f2], acc2[f2], 0, 0, 0);
      acc2[f2] = __builtin_amdgcn_mfma_f32_16x16x32_bf16(a1, wf1[f2], acc2[f2], 0, 0, 0);
    }
    #pragma unroll
    for (int f2 = 0; f2 < 4; ++f2) {
      #pragma unroll
      for (int reg = 0; reg < 4; ++reg) {
        int nb = wid * 64 + r2 * 16 + ((lane >> 4) << 2) + reg;
        float zl = acc2[f2][reg] + bl[f2];
        float zr = acc2[f2 + 4][reg] + bl[f2 + 4];
        float ov = zl * sigf(zr);
        int n = n0 + (nb >> 1);
        int b = b0 + (nb & 1);
        int co = f2 * 16 + (lane & 15);
        out[(size_t)((t * N_DIM + n) * B_DIM + b) * C_OUT + co] = ov;
      }
    }
  }
}

extern "C" void kernel_launch(void* const* d_in, const int* in_sizes, int n_in,
                              void* d_out, int out_size, void* d_ws, size_t ws_size,
                              hipStream_t stream) {
  const float* x  = (const float*)d_in[0];
  const float* As = (const float*)d_in[1];
  const float* E1 = (const float*)d_in[2];
  const float* E2 = (const float*)d_in[3];
  const float* al = (const float*)d_in[4];
  const float* W  = (const float*)d_in[5];
  const float* bf = (const float*)d_in[6];
  float* out = (float*)d_out;

  char* ws = (char*)d_ws;
  unsigned short* XT = (unsigned short*)ws;                       // 50,331,648 B
  unsigned short* Ab = (unsigned short*)(ws + 50331648);          //  8,388,608 B
  unsigned short* WT = (unsigned short*)(ws + 58720256);          //     16,384 B
  float* dinv = (float*)(ws + 58736640);

  k_dinv<<<dim3(2080), dim3(256), 0, stream>>>(As, dinv, W, WT);
  k_prep2<<<dim3(8192), dim3(256), 0, stream>>>(As, E1, E2, al, dinv, Ab, x, XT);
  k_gemm<<<dim3(1536), dim3(256), 0, stream>>>(Ab, XT, WT, bf, out);
}

// Round 15
// 161.760 us; speedup vs baseline: 1.2324x; 1.0211x over previous
//
#include <hip/hip_runtime.h>
#include <hip/hip_bf16.h>
#include <stdint.h>

#define T_DIM 12
#define N_DIM 2048
#define B_DIM 16
#define C_IN  64
#define C_OUT 64
#define EMB   16
#define P_DIM 1024   // B_DIM*C_IN

typedef __attribute__((ext_vector_type(8))) short short8;
typedef __attribute__((ext_vector_type(4))) float f32x4;

static __device__ __forceinline__ unsigned short f2bf(float f) {
  union { float f; uint32_t u; } v; v.f = f;
  uint32_t u = v.u;
  return (unsigned short)((u + 0x7fffu + ((u >> 16) & 1u)) >> 16);
}

static __device__ __forceinline__ float sigf(float x) {
  return __builtin_amdgcn_rcpf(1.0f + __expf(-x));
}

// async global->LDS, 16B per lane; lds ptr wave-uniform base (+lane*16 by HW)
static __device__ __forceinline__ void gload16(const void* g, void* l) {
  __builtin_amdgcn_global_load_lds(
      (const __attribute__((address_space(1))) unsigned int*)g,
      (__attribute__((address_space(3))) unsigned int*)l, 16, 0, 0);
}

template<bool MAX>
static __device__ __forceinline__ float block_red(float v, float* red) {
  #pragma unroll
  for (int o = 32; o > 0; o >>= 1) {
    float t = __shfl_down(v, o, 64);
    v = MAX ? fmaxf(v, t) : (v + t);
  }
  __syncthreads();
  if ((threadIdx.x & 63) == 0) red[threadIdx.x >> 6] = v;
  __syncthreads();
  float r = red[0];
  #pragma unroll
  for (int w = 1; w < 4; ++w) r = MAX ? fmaxf(r, red[w]) : (r + red[w]);
  return r;
}

// ---------------- k_dinv: [0,2048) static row-sum d^-1/2 | [2048,2080) W^T pack
__launch_bounds__(256)
__global__ void k_dinv(const float* __restrict__ As, float* __restrict__ dinv,
                       const float* __restrict__ W, unsigned short* __restrict__ WT) {
  __shared__ float red[4];
  int bid = blockIdx.x, tid = threadIdx.x;
  if (bid < 2048) {
    int n = bid;
    float rs = 0.f;
    #pragma unroll
    for (int i = 0; i < N_DIM / 256; ++i)
      rs += fmaxf(As[(size_t)n * N_DIM + i * 256 + tid], 0.f);
    float grs = block_red<false>(rs, red);
    if (tid == 0) dinv[n] = rsqrtf(fmaxf(grs + 1.0f, 1e-12f));
  } else {
    int q = (bid - 2048) * 256 + tid;   // 8192 elems
    int j = q >> 6, c = q & 63;
    WT[q] = f2bf(W[c * 128 + j]);
  }
}

// ---------------- k_prep2: [0,2048) A-assemble (inline softmax) | [2048,8192) x-transpose
__launch_bounds__(256)
__global__ void k_prep2(const float* __restrict__ As, const float* __restrict__ E1,
                        const float* __restrict__ E2, const float* __restrict__ alpha,
                        const float* __restrict__ dinv, unsigned short* __restrict__ A,
                        const float* __restrict__ x, unsigned short* __restrict__ XT) {
  __shared__ float smf[64 * 65];
  int bid = blockIdx.x, tid = threadIdx.x;

  if (bid < 2048) {
    // ---- assemble A row n (2048 cols), softmax stats inline
    int n = bid;
    if (tid < EMB) smf[4 + tid] = E1[n * EMB + tid];
    __syncthreads();
    float e1s[EMB];
    #pragma unroll
    for (int e = 0; e < EMB; ++e) e1s[e] = smf[4 + e];

    float p[8];
    #pragma unroll
    for (int i = 0; i < 8; ++i) {
      int m = i * 256 + tid;
      float d = 0.f;
      #pragma unroll
      for (int e = 0; e < EMB; ++e) d += e1s[e] * E2[e * N_DIM + m];
      p[i] = fmaxf(d, 0.f);
    }
    float lmx = p[0];
    #pragma unroll
    for (int i = 1; i < 8; ++i) lmx = fmaxf(lmx, p[i]);
    float gmx = block_red<true>(lmx, smf);
    float ls = 0.f;
    #pragma unroll
    for (int i = 0; i < 8; ++i) ls += expf(p[i] - gmx);
    float gse = block_red<false>(ls, smf);

    float a = sigf(alpha[0]);
    float di_n = dinv[n], inv_se = 1.f / gse;
    float ca = a, cb = (1.f - a) * 0.5f;
    #pragma unroll
    for (int i = 0; i < 8; ++i) {
      int m = i * 256 + tid;
      float soft = expf(p[i] - gmx) * inv_se;
      float idm = (m == n) ? 1.f : 0.f;
      float sv = fmaxf(As[(size_t)n * N_DIM + m], 0.f) + idm;
      float val = ca * di_n * dinv[m] * sv + cb * (soft + idm);
      A[(size_t)n * N_DIM + m] = f2bf(val);
    }
  } else {
    // ---- x (t,m,p) f32 -> XT (t,p,m) bf16 via LDS tile transpose
    int xb = bid - 2048;
    int t = xb >> 9;
    int rem = xb & 511;
    int mt = rem >> 4, pt = rem & 15;
    int m0 = mt * 64, p0 = pt * 64;
    #pragma unroll
    for (int i = 0; i < 4; ++i) {
      int lin = i * 256 + tid;
      int mm = lin >> 4;
      int pp4 = lin & 15;
      const float4 v = *(const float4*)&x[(size_t)(t * N_DIM + m0 + mm) * P_DIM + p0 + pp4 * 4];
      smf[(pp4 * 4 + 0) * 65 + mm] = v.x;
      smf[(pp4 * 4 + 1) * 65 + mm] = v.y;
      smf[(pp4 * 4 + 2) * 65 + mm] = v.z;
      smf[(pp4 * 4 + 3) * 65 + mm] = v.w;
    }
    __syncthreads();
    #pragma unroll
    for (int i = 0; i < 2; ++i) {
      int lin = i * 256 + tid;
      int pp = lin >> 3;
      int mmb = (lin & 7) * 8;
      union { unsigned short s[8]; uint4 u; } pk;
      #pragma unroll
      for (int q = 0; q < 8; ++q) pk.s[q] = f2bf(smf[pp * 65 + mmb + q]);
      *(uint4*)&XT[(size_t)t * P_DIM * N_DIM + (size_t)(p0 + pp) * N_DIM + m0 + mmb] = pk.u;
    }
  }
}

// ---------------- fused GEMM (R7 champion + T1 XCD swizzle): Y = A @ XT^T, swiglu(Y@W+b)
// BM=BN=128, BK=64, 256 thr = 4 waves (2Mx2N), wave 64x64, acc[4][4].
// Single-buffer 2-barrier loop, 3 blocks/CU, grid 1536 = 2 exact rounds.
// T1: v = (bid&7)*192 + bid>>3 (bijective) groups each pf-panel's 16 mb-sharers
// plus ~6 consecutive pf-groups (~3MB XT, L2-fit) onto one XCD -> cuts XT HBM
// re-fetch (FETCH 210MB with round-robin placement).
// Measured (R7/R13/R14): 117 us, MfmaUtil 41.5% = LDS-BW ceiling (96KB/iter
// / 155cy = 634 B/cy demand vs 256 B/cy supply). Structure frozen.
__launch_bounds__(256, 3)
__global__ void k_gemm(const unsigned short* __restrict__ A,   // 2048x2048 bf16
                       const unsigned short* __restrict__ XT,  // 12288 x 2048 bf16 (flat)
                       const unsigned short* __restrict__ WT,  // 128 x 64 bf16
                       const float* __restrict__ bfc,          // 128 f32
                       float* __restrict__ out) {
  __shared__ __align__(16) char lds[32768];   // A 16K + B 16K; Ys 32K overlay

  int bid0 = blockIdx.x;
  int v = (bid0 & 7) * 192 + (bid0 >> 3);   // XCD-contiguous remap (1536 = 8*192)
  int mb = v & 15;
  int pf = v >> 4;                // 0..95 (flat col group; never crosses t)
  int n0 = mb * 128;
  int p0f = pf * 128;
  int t = p0f >> 10;
  int b0 = (p0f & 1023) >> 6;

  int tid = threadIdx.x;
  int lane = tid & 63, wid = tid >> 6;
  int wr = wid >> 1, wc = wid & 1;       // 2M x 2N
  int wsd = wid * 1024;

  // staging source (pre-swizzled global -> linear LDS dest = swizzled layout)
  int srow = tid >> 3;                           // 0..31
  int scol = ((tid & 7) ^ (srow & 7)) * 8;       // swizzled 16B chunk in K=64
  const unsigned short* gA = A + (size_t)(n0 + srow) * N_DIM + scol;
  const unsigned short* gB = XT + (size_t)(p0f + srow) * N_DIM + scol;

  // fragment read offsets (swizzled 128B rows)
  int rsw = ((lane >> 4) * 16) ^ ((lane & 7) << 4);
  int faoff = (wr * 64 + (lane & 15)) * 128 + rsw;
  int fboff = (wc * 64 + (lane & 15)) * 128 + rsw;

  f32x4 acc[4][4];
  #pragma unroll
  for (int m = 0; m < 4; ++m)
    #pragma unroll
    for (int n = 0; n < 4; ++n) acc[m][n] = (f32x4){0.f, 0.f, 0.f, 0.f};

  for (int j = 0; j < 32; ++j) {
    size_t ko = (size_t)j * 64;
    #pragma unroll
    for (int s = 0; s < 4; ++s) gload16(gA + s * 65536 + ko, lds + s * 4096 + wsd);
    #pragma unroll
    for (int s = 0; s < 4; ++s) gload16(gB + s * 65536 + ko, lds + 16384 + s * 4096 + wsd);
    __syncthreads();   // drains vmcnt -> staged tile visible

    short8 fa[4][2], fb[4][2];
    #pragma unroll
    for (int mi = 0; mi < 4; ++mi)
      #pragma unroll
      for (int kk = 0; kk < 2; ++kk)
        fa[mi][kk] = *(const short8*)(lds + ((faoff + mi * 2048) ^ (kk * 64)));
    #pragma unroll
    for (int ni = 0; ni < 4; ++ni)
      #pragma unroll
      for (int kk = 0; kk < 2; ++kk)
        fb[ni][kk] = *(const short8*)(lds + 16384 + ((fboff + ni * 2048) ^ (kk * 64)));
    #pragma unroll
    for (int mi = 0; mi < 4; ++mi)
      #pragma unroll
      for (int ni = 0; ni < 4; ++ni) {
        acc[mi][ni] = __builtin_amdgcn_mfma_f32_16x16x32_bf16(fa[mi][0], fb[ni][0], acc[mi][ni], 0, 0, 0);
        acc[mi][ni] = __builtin_amdgcn_mfma_f32_16x16x32_bf16(fa[mi][1], fb[ni][1], acc[mi][ni], 0, 0, 0);
      }
    __syncthreads();   // all reads done before next stage overwrites
  }

  // ---- epilogue: Ys (256 rows = n_local*2 + b_local, 64 cin, swizzled 128B rows)
  #pragma unroll
  for (int m = 0; m < 4; ++m) {
    #pragma unroll
    for (int n = 0; n < 4; ++n) {
      #pragma unroll
      for (int reg = 0; reg < 4; ++reg) {
        int rl = wr * 64 + m * 16 + ((lane >> 4) << 2) + reg;    // 0..127
        int cin = n * 16 + (lane & 15);                          // 0..63
        int nb = rl * 2 + wc;                                    // 0..255
        int byte = nb * 128 + ((cin * 2) ^ ((nb & 7) << 4));
        *(unsigned short*)(lds + byte) = f2bf(acc[m][n][reg]);
      }
    }
  }
  __syncthreads();

  // GEMM2: (256 x 64) @ (64 x 128) + b, swiglu. W^T from global (L2-hot).
  short8 wf0[8], wf1[8];
  float bl[8];
  #pragma unroll
  for (int f2 = 0; f2 < 8; ++f2) {
    int jc = f2 * 16 + (lane & 15);
    wf0[f2] = *(const short8*)((const char*)WT + jc * 128 + (lane >> 4) * 16);
    wf1[f2] = *(const short8*)((const char*)WT + jc * 128 + 64 + (lane >> 4) * 16);
    bl[f2] = bfc[jc];
  }

  #pragma unroll
  for (int r2 = 0; r2 < 4; ++r2) {
    int row = wid * 64 + r2 * 16 + (lane & 15);
    int cb = ((lane >> 4) * 16) ^ ((row & 7) << 4);
    short8 a0 = *(const short8*)(lds + (row * 128 + cb));
    short8 a1 = *(const short8*)(lds + ((row * 128 + cb) ^ 64));
    f32x4 acc2[8];
    #pragma unroll
    for (int f2 = 0; f2 < 8; ++f2) {
      acc2[f2] = (f32x4){0.f, 0.f, 0.f, 0.f};
      acc2[f2] = __builtin_amdgcn_mfma_f32_16x16x32_bf16(a0, wf0[f2], acc2[f2], 0, 0, 0);
      acc2[f2] = __builtin_amdgcn_mfma_f32_16x16x32_bf16(a1, wf1[f2], acc2[f2], 0, 0, 0);
    }
    #pragma unroll
    for (int f2 = 0; f2 < 4; ++f2) {
      #pragma unroll
      for (int reg = 0; reg < 4; ++reg) {
        int nb = wid * 64 + r2 * 16 + ((lane >> 4) << 2) + reg;
        float zl = acc2[f2][reg] + bl[f2];
        float zr = acc2[f2 + 4][reg] + bl[f2 + 4];
        float ov = zl * sigf(zr);
        int n = n0 + (nb >> 1);
        int b = b0 + (nb & 1);
        int co = f2 * 16 + (lane & 15);
        out[(size_t)((t * N_DIM + n) * B_DIM + b) * C_OUT + co] = ov;
      }
    }
  }
}

extern "C" void kernel_launch(void* const* d_in, const int* in_sizes, int n_in,
                              void* d_out, int out_size, void* d_ws, size_t ws_size,
                              hipStream_t stream) {
  const float* x  = (const float*)d_in[0];
  const float* As = (const float*)d_in[1];
  const float* E1 = (const float*)d_in[2];
  const float* E2 = (const float*)d_in[3];
  const float* al = (const float*)d_in[4];
  const float* W  = (const float*)d_in[5];
  const float* bf = (const float*)d_in[6];
  float* out = (float*)d_out;

  char* ws = (char*)d_ws;
  unsigned short* XT = (unsigned short*)ws;                       // 50,331,648 B
  unsigned short* Ab = (unsigned short*)(ws + 50331648);          //  8,388,608 B
  unsigned short* WT = (unsigned short*)(ws + 58720256);          //     16,384 B
  float* dinv = (float*)(ws + 58736640);

  k_dinv<<<dim3(2080), dim3(256), 0, stream>>>(As, dinv, W, WT);
  k_prep2<<<dim3(8192), dim3(256), 0, stream>>>(As, E1, E2, al, dinv, Ab, x, XT);
  k_gemm<<<dim3(1536), dim3(256), 0, stream>>>(Ab, XT, WT, bf, out);
}